// Round 9
// baseline (298.553 us; speedup 1.0000x reference)
//
#include <hip/hip_runtime.h>
#include <stdint.h>

#define B_ 64
#define C_ 4
#define R_ 64
#define E_ 512
#define P_ 4
#define OS_ 256
#define L_ 32768          // R_*E_
#define K_ 131072         // L_*P_
#define M_ 256            // B_*C_

#define Z_ 128            // split-K slices (KCH=1024, two 512-k W phases/block)

#define XSTR 513          // padded x-row stride (f32): bank=(bcl+e)%32

typedef float  floatx4 __attribute__((ext_vector_type(4)));
typedef short  shortx8 __attribute__((ext_vector_type(8)));

static __device__ __forceinline__ unsigned short f2bf(float f) {
  union { float f; unsigned int u; } v; v.f = f;
  unsigned int u = v.u;
  u += 0x7fffu + ((u >> 16) & 1u);   // RNE
  return (unsigned short)(u >> 16);
}

// ---------------------------------------------------------------------------
// build_A (R6-verified, unchanged): x -> A2[k8][bc][8] bf16 k-slab granules.
// Contiguous half-wave stores + XSTR=513 conflict-free gather.
// ---------------------------------------------------------------------------
__global__ __launch_bounds__(512) void build_A(
    const float* __restrict__ x, const int* __restrict__ rxd_perm,
    const int* __restrict__ e_idx, const float* __restrict__ signs,
    unsigned short* __restrict__ A2) {
  __shared__ __align__(16) float xr[32 * XSTR];   // 65664 B
  const int t    = threadIdx.x;
  const int lane = t & 63;
  const int wv   = t >> 6;

  const int blk = blockIdx.x;           // 0..511
  const int r   = blk >> 3;
  const int bcg = blk & 7;
  const int pr  = rxd_perm[r];

  #pragma unroll
  for (int i = 0; i < 2; ++i) {
    const int row = wv * 4 + i * 2 + (lane >> 5);
    const float* xsrc = x + ((size_t)(bcg * 32 + row) * R_ + pr) * E_;
    float* xd = xr + (size_t)row * XSTR;
    #pragma unroll
    for (int pass = 0; pass < 8; ++pass) {
      const int e = pass * 64 + (lane & 31) * 2;
      const float2 v = *(const float2*)(xsrc + e);
      xd[e]     = v.x;
      xd[e + 1] = v.y;
    }
  }
  __syncthreads();

  const int bcl = t & 31;
  const int bc  = bcg * 32 + bcl;
  const float* xp = xr + (size_t)bcl * XSTR;

  #pragma unroll 1
  for (int task = 0; task < 4; ++task) {
    const int l  = task * 16 + (t >> 5);   // e-granule (same per half-wave)
    const int e0 = l * 8;

    float v[4][8];
    #pragma unroll
    for (int i = 0; i < 8; ++i) {
      const uint4  ei = *(const uint4*)(e_idx + (size_t)(e0 + i) * 4);
      const float4 sg = *(const float4*)(signs + (size_t)(e0 + i) * 4);
      v[0][i] = xp[ei.x] * sg.x;
      v[1][i] = xp[ei.y] * sg.y;
      v[2][i] = xp[ei.z] * sg.z;
      v[3][i] = xp[ei.w] * sg.w;
    }

    unsigned short* dst = A2 + ((size_t)(r * 64 + l) * 256 + bc) * 8;
    shortx8 o;

    #pragma unroll
    for (int i = 0; i < 8; ++i) o[i] = (short)f2bf(v[0][i]);
    *(shortx8*)(dst) = o;

    #pragma unroll
    for (int j = 0; j < 4; ++j) {
      const float a = v[1][2 * j], b = v[1][2 * j + 1];
      const bool first = (a >= b);
      o[2 * j]     = (short)f2bf(first ? a : 0.0f);
      o[2 * j + 1] = (short)f2bf(first ? 0.0f : b);
    }
    *(shortx8*)(dst + (size_t)4096 * 256 * 8) = o;

    #pragma unroll
    for (int j = 0; j < 2; ++j) {
      int am = 0; float m = v[2][4 * j];
      #pragma unroll
      for (int i = 1; i < 4; ++i)
        if (v[2][4 * j + i] > m) { m = v[2][4 * j + i]; am = i; }
      #pragma unroll
      for (int i = 0; i < 4; ++i) o[4 * j + i] = (short)f2bf(i == am ? m : 0.0f);
    }
    *(shortx8*)(dst + (size_t)2 * 4096 * 256 * 8) = o;

    {
      int am = 0; float m = v[3][0];
      #pragma unroll
      for (int i = 1; i < 8; ++i)
        if (v[3][i] > m) { m = v[3][i]; am = i; }
      #pragma unroll
      for (int i = 0; i < 8; ++i) o[i] = (short)f2bf(i == am ? m : 0.0f);
    }
    *(shortx8*)(dst + (size_t)3 * 4096 * 256 * 8) = o;
  }
}

// ---------------------------------------------------------------------------
// gemm_fw v2: fused W-conversion + split-K GEMM.
// R9 changes vs R8 (which measured 86 µs, FETCH 165MB, VGPR 52):
//  (1) 4-deep register prefetch of A-fragments (8 loads in flight/wave; R8's
//      load-use adjacency left only ~2 -> L3-latency-bound at 2.7 TB/s)
//  (2) Z=128, two 512-k W phases per block (acc carried, Ws restaged once):
//      halves Pp round-trip traffic (67 -> 33.5 MB)
// Block (z 0..127, ny 0..3): W tile [64n][512k] resident in 64 KB LDS per
// phase; A-fragments direct global->VGPR (L3-hot, ~88% absorbed per R8).
// ---------------------------------------------------------------------------
__global__ __launch_bounds__(512, 4) void gemm_fw(
    const unsigned short* __restrict__ A2, const float* __restrict__ W,
    float* __restrict__ Pp) {
  __shared__ unsigned short Ws[64 * 64 * 8];   // 64 KB: granule (k8, n^k8)
  const int t    = threadIdx.x;
  const int lane = t & 63;
  const int wv   = t >> 6;                  // 0..7
  const int id   = blockIdx.x;              // 0..511
  const int z    = id & 127;
  const int ny   = id >> 7;                 // 0..3
  const int lrow = lane & 15;
  const int quad = lane >> 4;

  floatx4 acc[2][4];
  #pragma unroll
  for (int i = 0; i < 2; ++i)
    #pragma unroll
    for (int j = 0; j < 4; ++j) acc[i][j] = {0.f, 0.f, 0.f, 0.f};

  const float* wb0 = W + (size_t)(ny * 64) * K_ + (size_t)z * 1024 + lane * 8;

  #pragma unroll 1
  for (int h = 0; h < 2; ++h) {
    // ---- stage W phase h: 64 rows x 512 f32; 16 batched dwordx4/thread ----
    const float* wb = wb0 + h * 512;
    float4 wa[8][2];
    #pragma unroll
    for (int i = 0; i < 8; ++i) {
      const float* wp = wb + (size_t)(wv * 8 + i) * K_;
      wa[i][0] = *(const float4*)(wp);
      wa[i][1] = *(const float4*)(wp + 4);
    }
    if (h) __syncthreads();                 // all waves done reading phase-0 Ws
    #pragma unroll
    for (int i = 0; i < 8; ++i) {
      shortx8 g;
      g[0] = (short)f2bf(wa[i][0].x); g[1] = (short)f2bf(wa[i][0].y);
      g[2] = (short)f2bf(wa[i][0].z); g[3] = (short)f2bf(wa[i][0].w);
      g[4] = (short)f2bf(wa[i][1].x); g[5] = (short)f2bf(wa[i][1].y);
      g[6] = (short)f2bf(wa[i][1].z); g[7] = (short)f2bf(wa[i][1].w);
      *(shortx8*)(&Ws[((size_t)lane * 64 + ((wv * 8 + i) ^ lane)) * 8]) = g;
    }
    __syncthreads();                        // Ws resident for this phase

    // a-frag granule base for this phase: k8 = z*128 + h*64 + s*4 + quad
    const unsigned short* ab =
        A2 + ((size_t)(z * 128 + h * 64 + quad) * 256 + wv * 32 + lrow) * 8;

    // 4-deep prefetch queue (statically indexed; s-loop fully unrolled)
    shortx8 pf0[4], pf1[4];
    #pragma unroll
    for (int s = 0; s < 4; ++s) {
      pf0[s] = *(const shortx8*)(ab + (size_t)s * 8192);
      pf1[s] = *(const shortx8*)(ab + (size_t)s * 8192 + 128);
    }

    #pragma unroll
    for (int s = 0; s < 16; ++s) {
      const shortx8 af0 = pf0[s & 3];
      const shortx8 af1 = pf1[s & 3];
      if (s < 12) {                         // refill slot with s+4
        pf0[s & 3] = *(const shortx8*)(ab + (size_t)(s + 4) * 8192);
        pf1[s & 3] = *(const shortx8*)(ab + (size_t)(s + 4) * 8192 + 128);
      }
      const int k8l = s * 4 + quad;
      shortx8 wf[4];
      #pragma unroll
      for (int tj = 0; tj < 4; ++tj)
        wf[tj] = *(const shortx8*)(&Ws[((size_t)k8l * 64 + ((tj * 16 + lrow) ^ k8l)) * 8]);
      #pragma unroll
      for (int tj = 0; tj < 4; ++tj) {
        acc[0][tj] = __builtin_amdgcn_mfma_f32_16x16x32_bf16(af0, wf[tj], acc[0][tj], 0, 0, 0);
        acc[1][tj] = __builtin_amdgcn_mfma_f32_16x16x32_bf16(af1, wf[tj], acc[1][tj], 0, 0, 0);
      }
    }
  }

  // epilogue: plain stores of the split-K partial slice [256 m][64 n]
  float* Pz = Pp + (size_t)z * (M_ * OS_) + ny * 64;
  #pragma unroll
  for (int ti = 0; ti < 2; ++ti)
    #pragma unroll
    for (int tj = 0; tj < 4; ++tj)
      #pragma unroll
      for (int j = 0; j < 4; ++j) {
        const int m = wv * 32 + ti * 16 + quad * 4 + j;
        const int n = tj * 16 + lrow;
        Pz[(size_t)m * OS_ + n] = acc[ti][tj][j];
      }
}

// out[m,n] = bias[n] + sum_z P[z,m,n]; 2-way z-split (64+64), LDS combine
__global__ __launch_bounds__(256) void reduce_out(
    const float* __restrict__ Pp, const float* __restrict__ bias,
    float* __restrict__ out) {
  __shared__ float4 part[128];
  const int t    = threadIdx.x;                    // 0..255
  const int i4   = blockIdx.x * 128 + (t & 127);   // 0..16383
  const int half = t >> 7;
  const float* p = Pp + (size_t)i4 * 4 + (size_t)half * 64 * (M_ * OS_);
  float4 s = {0.f, 0.f, 0.f, 0.f};
  #pragma unroll 8
  for (int zz = 0; zz < 64; ++zz) {
    const float4 v = *(const float4*)(p + (size_t)zz * (M_ * OS_));
    s.x += v.x; s.y += v.y; s.z += v.z; s.w += v.w;
  }
  if (half) part[t & 127] = s;
  __syncthreads();
  if (!half) {
    const float4 q = part[t];
    const float4 bb = *(const float4*)(bias + ((i4 * 4) & (OS_ - 1)));
    float4 o = {s.x + q.x + bb.x, s.y + q.y + bb.y,
                s.z + q.z + bb.z, s.w + q.w + bb.w};
    *(float4*)(out + (size_t)i4 * 4) = o;
  }
}

extern "C" void kernel_launch(void* const* d_in, const int* in_sizes, int n_in,
                              void* d_out, int out_size, void* d_ws, size_t ws_size,
                              hipStream_t stream) {
  const float* x        = (const float*)d_in[0];
  const int*   rxd_perm = (const int*)d_in[1];
  const int*   e_idx    = (const int*)d_in[2];
  const float* signs    = (const float*)d_in[3];
  const float* W        = (const float*)d_in[4];
  const float* bias     = (const float*)d_in[5];
  float* out = (float*)d_out;

  unsigned short* A2 = (unsigned short*)d_ws;                    // 67.1 MB
  float*          Pp = (float*)((char*)d_ws + 67108864);         // 33.5 MB

  build_A<<<dim3(512), dim3(512), 0, stream>>>(x, rxd_perm, e_idx, signs, A2);
  gemm_fw<<<dim3(512), dim3(512), 0, stream>>>(A2, W, Pp);
  reduce_out<<<dim3(128), dim3(256), 0, stream>>>(Pp, bias, out);
}